// Round 1
// baseline (243.245 us; speedup 1.0000x reference)
//
#include <hip/hip_runtime.h>
#include <math.h>

#define Bb 8
#define Nn 2048
#define Ff 64
#define ALPHA 0.2f
#define LN_EPS 1e-5f
#define NEG_BIG -9.0e15f

// ---------------- Kernel A: pack adj (int32 0/1) into bitmask ----------------
__global__ __launch_bounds__(256) void pack_mask(const int* __restrict__ adj,
                                                 unsigned int* __restrict__ bits) {
    int g = blockIdx.x * blockDim.x + threadIdx.x;   // element index, grid covers N*N exactly
    int lane = threadIdx.x & 63;
    int pred = adj[g] > 0;
    unsigned long long b = __ballot(pred);
    if ((lane & 31) == 0) {
        bits[g >> 5] = (unsigned int)(b >> (lane & 32));
    }
}

// ---------------- Kernel B: x-scale, h = x@W, LayerNorm, s1/s2 ----------------
__global__ __launch_bounds__(256) void node_transform(
    const float* __restrict__ in, const float* __restrict__ W,
    const float* __restrict__ a, const float* __restrict__ nw,
    const float* __restrict__ nb, const float* __restrict__ gam,
    const float* __restrict__ bet,
    float* __restrict__ h, float* __restrict__ s1, float* __restrict__ s2)
{
    __shared__ float Wl[64 * 64];
    int t = threadIdx.x;
#pragma unroll
    for (int s = 0; s < 16; ++s) Wl[t + 256 * s] = W[t + 256 * s];
    __syncthreads();
    int wave = t >> 6, lane = t & 63;
    int node = blockIdx.x * 4 + wave;        // 4096 blocks x 4 waves = 16384 nodes
    int n = node & (Nn - 1);
    float xv = in[node * 64 + lane] * (nw[n] + 1.0f) + nb[n];
    float hv = 0.f;
#pragma unroll
    for (int k = 0; k < 64; ++k)
        hv = fmaf(__shfl(xv, k, 64), Wl[k * 64 + lane], hv);
    // LayerNorm over 64 lanes
    float mu = hv;
#pragma unroll
    for (int o = 32; o; o >>= 1) mu += __shfl_xor(mu, o, 64);
    mu *= (1.f / 64.f);
    float d = hv - mu;
    float var = d * d;
#pragma unroll
    for (int o = 32; o; o >>= 1) var += __shfl_xor(var, o, 64);
    var *= (1.f / 64.f);
    float hn = d * rsqrtf(var + LN_EPS) * gam[lane] + bet[lane];
    h[node * 64 + lane] = hn;
    float p1 = hn * a[lane];         // a1 = a[0:64,0]
    float p2 = hn * a[64 + lane];    // a2 = a[64:128,0]
#pragma unroll
    for (int o = 32; o; o >>= 1) {
        p1 += __shfl_xor(p1, o, 64);
        p2 += __shfl_xor(p2, o, 64);
    }
    if (lane == 0) { s1[node] = p1; s2[node] = p2; }
}

// ---------------- Kernel C: fused masked softmax + att@h + residual + elu ----
// grid (32, 8): blockIdx.x = i-tile (64 rows), blockIdx.y = batch. 512 threads (8 waves).
__global__ __launch_bounds__(512) void attention(
    const float* __restrict__ h, const float* __restrict__ s1g,
    const float* __restrict__ s2g, const unsigned int* __restrict__ bits,
    float* __restrict__ out)
{
    __shared__ float s2l[Nn];          // 8 KB
    __shared__ float s1l[64];
    __shared__ float ht[64][68];       // transposed h tile [f][j_local], padded
    __shared__ float wl[64][64];       // unnormalized p tile

    int t = threadIdx.x, wave = t >> 6, lane = t & 63;
    int i0 = blockIdx.x * 64;
    int bb = blockIdx.y;
    const float* hb = h + (size_t)bb * Nn * 64;

    for (int s = t; s < Nn; s += 512) s2l[s] = s2g[bb * Nn + s];
    if (t < 64) s1l[t] = s1g[bb * Nn + i0 + t];
    __syncthreads();

    // each wave owns 8 rows: i = i0 + wave*8 + ii
    unsigned int maskw[8];
    float m[8];
#pragma unroll
    for (int ii = 0; ii < 8; ++ii) {
        int i = i0 + wave * 8 + ii;
        maskw[ii] = bits[i * 64 + lane];   // 64 words = full 2048-bit row
    }
    // ---- phase 1: row max of masked leaky_relu(s1+s2) ----
#pragma unroll
    for (int ii = 0; ii < 8; ++ii) {
        float s1v = s1l[wave * 8 + ii];
        float mp = NEG_BIG;
        for (int c = 0; c < 32; ++c) {
            unsigned int wd = __shfl(maskw[ii], (c << 1) | (lane >> 5), 64);
            int bit = (wd >> (lane & 31)) & 1;
            float x = s1v + s2l[c * 64 + lane];
            float e = bit ? (x >= 0.f ? x : ALPHA * x) : NEG_BIG;
            mp = fmaxf(mp, e);
        }
#pragma unroll
        for (int o = 32; o; o >>= 1) mp = fmaxf(mp, __shfl_xor(mp, o, 64));
        m[ii] = mp;
    }

    // ---- phase 2: unnormalized p, Z partial, PV accumulate ----
    float acc[8], zp[8];
#pragma unroll
    for (int ii = 0; ii < 8; ++ii) { acc[ii] = 0.f; zp[ii] = 0.f; }

    for (int c = 0; c < 32; ++c) {
        __syncthreads();   // previous chunk's readers done before restage
        // stage transposed h tile: 4096 floats, 512 threads x 2 float4
#pragma unroll
        for (int s = 0; s < 2; ++s) {
            int slot = t + s * 512;          // float4 slot 0..1023
            int jl = slot >> 4, f4 = slot & 15;
            float4 v = *(const float4*)&hb[(size_t)(c * 64 + jl) * 64 + f4 * 4];
            ht[f4 * 4 + 0][jl] = v.x;
            ht[f4 * 4 + 1][jl] = v.y;
            ht[f4 * 4 + 2][jl] = v.z;
            ht[f4 * 4 + 3][jl] = v.w;
        }
        // p tile for this wave's rows (lane = j within chunk)
#pragma unroll
        for (int ii = 0; ii < 8; ++ii) {
            int r = wave * 8 + ii;
            unsigned int wd = __shfl(maskw[ii], (c << 1) | (lane >> 5), 64);
            int bit = (wd >> (lane & 31)) & 1;
            float x = s1l[r] + s2l[c * 64 + lane];
            float e = bit ? (x >= 0.f ? x : ALPHA * x) : NEG_BIG;
            float p = __expf(e - m[ii]);
            wl[r][lane] = p;
            zp[ii] += p;
        }
        __syncthreads();   // ht + wl ready
        // PV: lane = f; h columns in registers, reused across 8 rows
        float4 hr[16];
#pragma unroll
        for (int q = 0; q < 16; ++q) hr[q] = *(const float4*)&ht[lane][q * 4];
#pragma unroll
        for (int ii = 0; ii < 8; ++ii) {
            int r = wave * 8 + ii;
            float a_ = acc[ii];
#pragma unroll
            for (int q = 0; q < 16; ++q) {
                float4 w4 = *(const float4*)&wl[r][q * 4];   // wave-uniform broadcast
                a_ = fmaf(w4.x, hr[q].x, a_);
                a_ = fmaf(w4.y, hr[q].y, a_);
                a_ = fmaf(w4.z, hr[q].z, a_);
                a_ = fmaf(w4.w, hr[q].w, a_);
            }
            acc[ii] = a_;
        }
    }

    // ---- finalize: normalize, residual, elu ----
#pragma unroll
    for (int ii = 0; ii < 8; ++ii) {
        float z = zp[ii];
#pragma unroll
        for (int o = 32; o; o >>= 1) z += __shfl_xor(z, o, 64);
        float zinv = 1.0f / z;
        int i = i0 + wave * 8 + ii;
        float hp = acc[ii] * zinv + hb[(size_t)i * 64 + lane];
        out[((size_t)bb * Nn + i) * 64 + lane] = hp > 0.f ? hp : expm1f(hp);
    }
}

// ---------------- launch ----------------
extern "C" void kernel_launch(void* const* d_in, const int* in_sizes, int n_in,
                              void* d_out, int out_size, void* d_ws, size_t ws_size,
                              hipStream_t stream) {
    const float* in  = (const float*)d_in[0];
    const int*   adj = (const int*)d_in[1];
    const float* W   = (const float*)d_in[2];
    const float* a   = (const float*)d_in[3];
    const float* nw  = (const float*)d_in[4];
    const float* nb  = (const float*)d_in[5];
    const float* gam = (const float*)d_in[6];
    const float* bet = (const float*)d_in[7];
    float* out = (float*)d_out;

    char* ws = (char*)d_ws;
    float* h  = (float*)ws;                                   // B*N*F floats = 4 MB
    float* s1 = (float*)(ws + (size_t)Bb * Nn * Ff * 4);      // 64 KB
    float* s2 = s1 + (size_t)Bb * Nn;                         // 64 KB
    unsigned int* bits = (unsigned int*)(s2 + (size_t)Bb * Nn); // N*64 words = 512 KB

    hipLaunchKernelGGL(pack_mask, dim3(Nn * Nn / 256), dim3(256), 0, stream, adj, bits);
    hipLaunchKernelGGL(node_transform, dim3(Bb * Nn / 4), dim3(256), 0, stream,
                       in, W, a, nw, nb, gam, bet, h, s1, s2);
    hipLaunchKernelGGL(attention, dim3(Nn / 64, Bb), dim3(512), 0, stream,
                       h, s1, s2, bits, out);
}

// Round 2
// 92.436 us; speedup vs baseline: 2.6315x; 2.6315x over previous
//
#include <hip/hip_runtime.h>
#include <math.h>

#define Bb 8
#define Nn 2048
#define Ff 64
#define ALPHA 0.2f
#define LN_EPS 1e-5f

typedef __attribute__((ext_vector_type(8))) short short8;
typedef __attribute__((ext_vector_type(4))) float f32x4;

__device__ inline unsigned short f2bf(float f) {
    unsigned u = __builtin_bit_cast(unsigned, f);
    u += 0x7fffu + ((u >> 16) & 1u);   // round-to-nearest-even
    return (unsigned short)(u >> 16);
}

// ---------------- Kernel A: pack adj (int32 0/1) into bitmask ----------------
__global__ __launch_bounds__(256) void pack_mask(const int* __restrict__ adj,
                                                 unsigned int* __restrict__ bits) {
    int g = blockIdx.x * blockDim.x + threadIdx.x;
    int lane = threadIdx.x & 63;
    int pred = adj[g] > 0;
    unsigned long long b = __ballot(pred);
    if ((lane & 31) == 0) {
        bits[g >> 5] = (unsigned int)(b >> (lane & 32));
    }
}

// ---------------- Kernel B: x-scale, h = x@W, LayerNorm, s1/s2 ----------------
__global__ __launch_bounds__(256) void node_transform(
    const float* __restrict__ in, const float* __restrict__ W,
    const float* __restrict__ a, const float* __restrict__ nw,
    const float* __restrict__ nb, const float* __restrict__ gam,
    const float* __restrict__ bet,
    float* __restrict__ h, float* __restrict__ s1, float* __restrict__ s2)
{
    __shared__ float Wl[64 * 64];
    int t = threadIdx.x;
#pragma unroll
    for (int s = 0; s < 16; ++s) Wl[t + 256 * s] = W[t + 256 * s];
    __syncthreads();
    int wave = t >> 6, lane = t & 63;
    int node = blockIdx.x * 4 + wave;
    int n = node & (Nn - 1);
    float xv = in[node * 64 + lane] * (nw[n] + 1.0f) + nb[n];
    float hv = 0.f;
#pragma unroll
    for (int k = 0; k < 64; ++k)
        hv = fmaf(__shfl(xv, k, 64), Wl[k * 64 + lane], hv);
    float mu = hv;
#pragma unroll
    for (int o = 32; o; o >>= 1) mu += __shfl_xor(mu, o, 64);
    mu *= (1.f / 64.f);
    float d = hv - mu;
    float var = d * d;
#pragma unroll
    for (int o = 32; o; o >>= 1) var += __shfl_xor(var, o, 64);
    var *= (1.f / 64.f);
    float hn = d * rsqrtf(var + LN_EPS) * gam[lane] + bet[lane];
    h[node * 64 + lane] = hn;
    float p1 = hn * a[lane];
    float p2 = hn * a[64 + lane];
#pragma unroll
    for (int o = 32; o; o >>= 1) {
        p1 += __shfl_xor(p1, o, 64);
        p2 += __shfl_xor(p2, o, 64);
    }
    if (lane == 0) { s1[node] = p1; s2[node] = p2; }
}

// ---------------- Kernel B2: transpose h -> hT bf16 [b][f][j] ----------------
__global__ __launch_bounds__(256) void transpose_h(const float* __restrict__ h,
                                                   unsigned short* __restrict__ hT) {
    int b = blockIdx.y, jt = blockIdx.x, t = threadIdx.x;
    for (int s = t; s < 1024; s += 256) {
        int fq = s & 15, j = s >> 4;                 // coalesced read: 16 lanes cover a row
        int col = jt * 64 + j;
        float4 v = *(const float4*)&h[((size_t)(b * Nn + col)) * 64 + fq * 4];
        unsigned short* base = hT + ((size_t)b * 64 + fq * 4) * Nn + col;
        base[0 * Nn] = f2bf(v.x);
        base[1 * Nn] = f2bf(v.y);
        base[2 * Nn] = f2bf(v.z);
        base[3 * Nn] = f2bf(v.w);
    }
}

// ---------------- Kernel C: fused no-max softmax + MFMA PV + residual + elu --
// grid (128, 8): 16 i-rows per block, 128 threads (2 waves).
__global__ __launch_bounds__(128) void attention2(
    const float* __restrict__ h, const unsigned short* __restrict__ hT,
    const float* __restrict__ s1g, const float* __restrict__ s2g,
    const unsigned int* __restrict__ bits, float* __restrict__ out)
{
    __shared__ float s2l[Nn];                        // 8 KB
    __shared__ __align__(16) unsigned short p_lds[16][72]; // bf16 P tile, 144B rows
    __shared__ float zinv_l[16];

    int t = threadIdx.x, wave = t >> 6, lane = t & 63;
    int i0 = blockIdx.x * 16, b = blockIdx.y;

    for (int s = t; s < Nn / 4; s += 128)
        *(float4*)&s2l[s * 4] = *(const float4*)&s2g[b * Nn + s * 4];

    float s1r[8];
    unsigned int maskw[8];
#pragma unroll
    for (int ii = 0; ii < 8; ++ii) {
        int i = i0 + wave * 8 + ii;
        s1r[ii] = s1g[b * Nn + i];
        maskw[ii] = bits[i * 64 + lane];             // full 2048-bit row in regs
    }
    __syncthreads();

    f32x4 acc0 = {0.f, 0.f, 0.f, 0.f}, acc1 = {0.f, 0.f, 0.f, 0.f};
    float zp[8];
#pragma unroll
    for (int ii = 0; ii < 8; ++ii) zp[ii] = 0.f;

    const unsigned short* hTb = hT + (size_t)b * 64 * Nn;
    int fb0 = wave * 2, fb1 = wave * 2 + 1;
    int am = lane & 15, ag = lane >> 4;

    for (int c = 0; c < 32; ++c) {
        // ---- P tile (natural layout, lane = j), no max subtraction ----
#pragma unroll
        for (int ii = 0; ii < 8; ++ii) {
            unsigned int wd = __shfl(maskw[ii], (c << 1) | (lane >> 5), 64);
            int bit = (wd >> (lane & 31)) & 1;
            float x = s1r[ii] + s2l[c * 64 + lane];
            float lr = x >= 0.f ? x : ALPHA * x;
            float p = bit ? __expf(lr) : 0.f;        // masked -> exactly 0
            zp[ii] += p;
            p_lds[wave * 8 + ii][lane] = f2bf(p);
        }
        __syncthreads();
        // ---- MFMA: P(16x64) @ hT(64x64) ----
#pragma unroll
        for (int kt = 0; kt < 2; ++kt) {
            short8 afrag = *(const short8*)&p_lds[am][kt * 32 + 8 * ag];
            int krow = c * 64 + kt * 32 + 8 * ag;
            short8 b0 = *(const short8*)&hTb[(size_t)(fb0 * 16 + am) * Nn + krow];
            short8 b1 = *(const short8*)&hTb[(size_t)(fb1 * 16 + am) * Nn + krow];
            acc0 = __builtin_amdgcn_mfma_f32_16x16x32_bf16(afrag, b0, acc0, 0, 0, 0);
            acc1 = __builtin_amdgcn_mfma_f32_16x16x32_bf16(afrag, b1, acc1, 0, 0, 0);
        }
        __syncthreads();
    }

    // ---- Z reduce ----
#pragma unroll
    for (int ii = 0; ii < 8; ++ii) {
        float z = zp[ii];
#pragma unroll
        for (int o = 32; o; o >>= 1) z += __shfl_xor(z, o, 64);
        if (lane == 0) zinv_l[wave * 8 + ii] = 1.f / z;
    }
    __syncthreads();

    // ---- epilogue: normalize, residual, elu ----
    const float* hb = h + (size_t)b * Nn * 64;
#pragma unroll
    for (int q = 0; q < 4; ++q) {
        int row = ag * 4 + q;
        int i = i0 + row;
        float zinv = zinv_l[row];
        size_t obase = ((size_t)(b * Nn + i)) * 64;
        float v0 = acc0[q] * zinv + hb[(size_t)i * 64 + fb0 * 16 + am];
        out[obase + fb0 * 16 + am] = v0 > 0.f ? v0 : expm1f(v0);
        float v1 = acc1[q] * zinv + hb[(size_t)i * 64 + fb1 * 16 + am];
        out[obase + fb1 * 16 + am] = v1 > 0.f ? v1 : expm1f(v1);
    }
}

// ---------------- launch ----------------
extern "C" void kernel_launch(void* const* d_in, const int* in_sizes, int n_in,
                              void* d_out, int out_size, void* d_ws, size_t ws_size,
                              hipStream_t stream) {
    const float* in  = (const float*)d_in[0];
    const int*   adj = (const int*)d_in[1];
    const float* W   = (const float*)d_in[2];
    const float* a   = (const float*)d_in[3];
    const float* nw  = (const float*)d_in[4];
    const float* nb  = (const float*)d_in[5];
    const float* gam = (const float*)d_in[6];
    const float* bet = (const float*)d_in[7];
    float* out = (float*)d_out;

    char* ws = (char*)d_ws;
    float* h  = (float*)ws;                                      // 4 MB
    float* s1 = (float*)(ws + (size_t)Bb * Nn * Ff * 4);         // 64 KB
    float* s2 = s1 + (size_t)Bb * Nn;                            // 64 KB
    unsigned int* bits = (unsigned int*)(s2 + (size_t)Bb * Nn);  // 512 KB
    unsigned short* hT = (unsigned short*)(bits + (size_t)Nn * Nn / 32); // 2 MB

    hipLaunchKernelGGL(pack_mask, dim3(Nn * Nn / 256), dim3(256), 0, stream, adj, bits);
    hipLaunchKernelGGL(node_transform, dim3(Bb * Nn / 4), dim3(256), 0, stream,
                       in, W, a, nw, nb, gam, bet, h, s1, s2);
    hipLaunchKernelGGL(transpose_h, dim3(Nn / 64, Bb), dim3(256), 0, stream, h, hT);
    hipLaunchKernelGGL(attention2, dim3(Nn / 16, Bb), dim3(128), 0, stream,
                       h, hT, s1, s2, bits, out);
}

// Round 3
// 86.657 us; speedup vs baseline: 2.8070x; 1.0667x over previous
//
#include <hip/hip_runtime.h>
#include <math.h>

#define Bb 8
#define Nn 2048
#define Ff 64
#define ALPHA 0.2f
#define LN_EPS 1e-5f

typedef __attribute__((ext_vector_type(8))) short short8;
typedef __attribute__((ext_vector_type(4))) float f32x4;

__device__ inline unsigned short f2bf(float f) {
    unsigned u = __builtin_bit_cast(unsigned, f);
    u += 0x7fffu + ((u >> 16) & 1u);   // round-to-nearest-even
    return (unsigned short)(u >> 16);
}

// ---------------- Kernel A: pack adj (int32 0/1) into bitmask ----------------
__global__ __launch_bounds__(256) void pack_mask(const int* __restrict__ adj,
                                                 unsigned int* __restrict__ bits) {
    int g = blockIdx.x * blockDim.x + threadIdx.x;
    int lane = threadIdx.x & 63;
    int pred = adj[g] > 0;
    unsigned long long b = __ballot(pred);
    if ((lane & 31) == 0) {
        bits[g >> 5] = (unsigned int)(b >> (lane & 32));
    }
}

// ------- Kernel B: x-scale, h=x@W, LayerNorm, s1/s2, h fp32 + hT bf16 -------
// 32 nodes/block (4 waves x 8 nodes). Grid 512.
__global__ __launch_bounds__(256) void node_transform(
    const float* __restrict__ in, const float* __restrict__ W,
    const float* __restrict__ a, const float* __restrict__ nw,
    const float* __restrict__ nb, const float* __restrict__ gam,
    const float* __restrict__ bet,
    float* __restrict__ h, float* __restrict__ s1, float* __restrict__ s2,
    unsigned short* __restrict__ hT)
{
    __shared__ float Wl[64 * 64];
    int t = threadIdx.x;
#pragma unroll
    for (int s = 0; s < 16; ++s) Wl[t + 256 * s] = W[t + 256 * s];
    __syncthreads();
    int wave = t >> 6, lane = t & 63;
    float ga = gam[lane], be = bet[lane];
    float a1 = a[lane], a2 = a[64 + lane];
    short8 h8;
#pragma unroll
    for (int nn = 0; nn < 8; ++nn) {
        int node = blockIdx.x * 32 + wave * 8 + nn;
        int n = node & (Nn - 1);
        float xv = in[node * 64 + lane] * (nw[n] + 1.0f) + nb[n];
        float hv0 = 0.f, hv1 = 0.f, hv2 = 0.f, hv3 = 0.f;
#pragma unroll
        for (int k4 = 0; k4 < 16; ++k4) {
            hv0 = fmaf(__shfl(xv, k4 * 4 + 0, 64), Wl[(k4 * 4 + 0) * 64 + lane], hv0);
            hv1 = fmaf(__shfl(xv, k4 * 4 + 1, 64), Wl[(k4 * 4 + 1) * 64 + lane], hv1);
            hv2 = fmaf(__shfl(xv, k4 * 4 + 2, 64), Wl[(k4 * 4 + 2) * 64 + lane], hv2);
            hv3 = fmaf(__shfl(xv, k4 * 4 + 3, 64), Wl[(k4 * 4 + 3) * 64 + lane], hv3);
        }
        float hv = (hv0 + hv1) + (hv2 + hv3);
        float mu = hv;
#pragma unroll
        for (int o = 32; o; o >>= 1) mu += __shfl_xor(mu, o, 64);
        mu *= (1.f / 64.f);
        float d = hv - mu;
        float var = d * d;
#pragma unroll
        for (int o = 32; o; o >>= 1) var += __shfl_xor(var, o, 64);
        var *= (1.f / 64.f);
        float hn = d * rsqrtf(var + LN_EPS) * ga + be;
        h[node * 64 + lane] = hn;
        h8[nn] = (short)f2bf(hn);
        float p1 = hn * a1, p2 = hn * a2;
#pragma unroll
        for (int o = 32; o; o >>= 1) {
            p1 += __shfl_xor(p1, o, 64);
            p2 += __shfl_xor(p2, o, 64);
        }
        if (lane == 0) { s1[node] = p1; s2[node] = p2; }
    }
    // hT write: row f=lane, cols (block nodes + wave*8 .. +7), 16B per lane
    int node0 = blockIdx.x * 32;
    int b = node0 >> 11, col = (node0 & (Nn - 1)) + wave * 8;
    *(short8*)&hT[((size_t)(b * 64 + lane)) * Nn + col] = h8;
}

// ---- Kernel C: barrier-free fused softmax + MFMA PV, in-LDS combine --------
// grid (64, 8): 32 rows/block, 512 thr = 8 waves: wave = (rg = w&1, jq = w>>1).
__global__ __launch_bounds__(512, 4) void attention3(
    const float* __restrict__ h, const unsigned short* __restrict__ hT,
    const float* __restrict__ s1g, const float* __restrict__ s2g,
    const unsigned int* __restrict__ bits, float* __restrict__ out)
{
    __shared__ float paccl[2][4][16][68];   // [rg][jq][row][f] padded
    __shared__ float zl[2][4][16];

    int t = threadIdx.x, wave = t >> 6, lane = t & 63;
    int am = lane & 15, ag = lane >> 4;
    int rg = wave & 1, jq = wave >> 1;
    int b = blockIdx.y;
    int i0 = blockIdx.x * 32 + rg * 16;
    int row = i0 + am;

    // mask: lane holds row (i0+am), words jq*16 + ag*4 .. +3
    uint4 mw = *(const uint4*)&bits[(size_t)row * 64 + jq * 16 + ag * 4];
    float s1r = s1g[b * Nn + row];
    const float* s2b = s2g + b * Nn + jq * 512;
    const unsigned short* hT0 = hT + ((size_t)(b * 64) + 0 * 16 + am) * Nn + jq * 512;
    const unsigned short* hT1 = hT + ((size_t)(b * 64) + 1 * 16 + am) * Nn + jq * 512;
    const unsigned short* hT2 = hT + ((size_t)(b * 64) + 2 * 16 + am) * Nn + jq * 512;
    const unsigned short* hT3 = hT + ((size_t)(b * 64) + 3 * 16 + am) * Nn + jq * 512;

    f32x4 acc0 = {0,0,0,0}, acc1 = {0,0,0,0}, acc2 = {0,0,0,0}, acc3 = {0,0,0,0};
    float zp = 0.f;

#pragma unroll
    for (int c = 0; c < 8; ++c) {
#pragma unroll
        for (int kt = 0; kt < 2; ++kt) {
            const int w = 2 * c + kt;                 // word idx 0..15 (literal)
            int src = am + 16 * (w >> 2);
            unsigned wd;
            switch (w & 3) {
                case 0:  wd = __shfl(mw.x, src, 64); break;
                case 1:  wd = __shfl(mw.y, src, 64); break;
                case 2:  wd = __shfl(mw.z, src, 64); break;
                default: wd = __shfl(mw.w, src, 64); break;
            }
            int kb = c * 64 + kt * 32 + 8 * ag;
            float4 sa = *(const float4*)&s2b[kb];
            float4 sb = *(const float4*)&s2b[kb + 4];
            float sev[8] = {sa.x, sa.y, sa.z, sa.w, sb.x, sb.y, sb.z, sb.w};
            short8 af;
#pragma unroll
            for (int e = 0; e < 8; ++e) {
                float x = s1r + sev[e];
                float lr = fmaxf(x, ALPHA * x);
                float p = ((wd >> (8 * ag + e)) & 1u) ? __expf(lr) : 0.f;
                zp += p;
                af[e] = (short)f2bf(p);
            }
            short8 b0 = *(const short8*)&hT0[kb];
            short8 b1 = *(const short8*)&hT1[kb];
            short8 b2 = *(const short8*)&hT2[kb];
            short8 b3 = *(const short8*)&hT3[kb];
            acc0 = __builtin_amdgcn_mfma_f32_16x16x32_bf16(af, b0, acc0, 0, 0, 0);
            acc1 = __builtin_amdgcn_mfma_f32_16x16x32_bf16(af, b1, acc1, 0, 0, 0);
            acc2 = __builtin_amdgcn_mfma_f32_16x16x32_bf16(af, b2, acc2, 0, 0, 0);
            acc3 = __builtin_amdgcn_mfma_f32_16x16x32_bf16(af, b3, acc3, 0, 0, 0);
        }
    }

    // Z partial for row am: reduce over ag groups
    zp += __shfl_xor(zp, 16, 64);
    zp += __shfl_xor(zp, 32, 64);
    if (lane < 16) zl[rg][jq][am] = zp;

    // acc tiles -> LDS: row_local = ag*4+q, f = fb*16+am
#pragma unroll
    for (int q = 0; q < 4; ++q) {
        paccl[rg][jq][ag * 4 + q][0 * 16 + am] = acc0[q];
        paccl[rg][jq][ag * 4 + q][1 * 16 + am] = acc1[q];
        paccl[rg][jq][ag * 4 + q][2 * 16 + am] = acc2[q];
        paccl[rg][jq][ag * 4 + q][3 * 16 + am] = acc3[q];
    }
    __syncthreads();

    // combine over jq + residual + elu. 512 thr over 32 rows x 16 fquads.
    int rl = t >> 4, fq = t & 15;
    int rg2 = rl >> 4, r16 = rl & 15;
    float zs = zl[rg2][0][r16] + zl[rg2][1][r16] + zl[rg2][2][r16] + zl[rg2][3][r16];
    float sx = 0.f, sy = 0.f, sz = 0.f, sw = 0.f;
#pragma unroll
    for (int q4 = 0; q4 < 4; ++q4) {
        const float* p = &paccl[rg2][q4][r16][fq * 4];
        sx += p[0]; sy += p[1]; sz += p[2]; sw += p[3];
    }
    float zinv = 1.f / zs;
    int gi = blockIdx.x * 32 + rl;
    size_t base = ((size_t)(b * Nn + gi)) * 64 + fq * 4;
    float4 hv = *(const float4*)&h[base];
    float4 o;
    o.x = sx * zinv + hv.x; o.x = o.x > 0.f ? o.x : expm1f(o.x);
    o.y = sy * zinv + hv.y; o.y = o.y > 0.f ? o.y : expm1f(o.y);
    o.z = sz * zinv + hv.z; o.z = o.z > 0.f ? o.z : expm1f(o.z);
    o.w = sw * zinv + hv.w; o.w = o.w > 0.f ? o.w : expm1f(o.w);
    *(float4*)&out[base] = o;
}

// ---------------- launch ----------------
extern "C" void kernel_launch(void* const* d_in, const int* in_sizes, int n_in,
                              void* d_out, int out_size, void* d_ws, size_t ws_size,
                              hipStream_t stream) {
    const float* in  = (const float*)d_in[0];
    const int*   adj = (const int*)d_in[1];
    const float* W   = (const float*)d_in[2];
    const float* a   = (const float*)d_in[3];
    const float* nw  = (const float*)d_in[4];
    const float* nb  = (const float*)d_in[5];
    const float* gam = (const float*)d_in[6];
    const float* bet = (const float*)d_in[7];
    float* out = (float*)d_out;

    char* ws = (char*)d_ws;
    float* h  = (float*)ws;                                      // 4 MB
    float* s1 = (float*)(ws + (size_t)Bb * Nn * Ff * 4);         // 64 KB
    float* s2 = s1 + (size_t)Bb * Nn;                            // 64 KB
    unsigned int* bits = (unsigned int*)(s2 + (size_t)Bb * Nn);  // 512 KB
    unsigned short* hT = (unsigned short*)(bits + (size_t)Nn * Nn / 32); // 2 MB

    hipLaunchKernelGGL(pack_mask, dim3(Nn * Nn / 256), dim3(256), 0, stream, adj, bits);
    hipLaunchKernelGGL(node_transform, dim3(Bb * Nn / 32), dim3(256), 0, stream,
                       in, W, a, nw, nb, gam, bet, h, s1, s2, hT);
    hipLaunchKernelGGL(attention3, dim3(Nn / 32, Bb), dim3(512), 0, stream,
                       h, hT, s1, s2, bits, out);
}

// Round 4
// 75.374 us; speedup vs baseline: 3.2272x; 1.1497x over previous
//
#include <hip/hip_runtime.h>
#include <math.h>

#define Bb 8
#define Nn 2048
#define Ff 64
#define ALPHA 0.2f
#define LN_EPS 1e-5f

typedef __attribute__((ext_vector_type(8))) short short8;
typedef __attribute__((ext_vector_type(4))) float f32x4;

__device__ inline unsigned short f2bf(float f) {
    unsigned u = __builtin_bit_cast(unsigned, f);
    u += 0x7fffu + ((u >> 16) & 1u);   // round-to-nearest-even
    return (unsigned short)(u >> 16);
}

// ---------------- Kernel A: pack adj (int32 0/1) into bitmask ----------------
__global__ __launch_bounds__(256) void pack_mask(const int* __restrict__ adj,
                                                 unsigned int* __restrict__ bits) {
    int g = blockIdx.x * blockDim.x + threadIdx.x;
    int lane = threadIdx.x & 63;
    int pred = adj[g] > 0;
    unsigned long long b = __ballot(pred);
    if ((lane & 31) == 0) {
        bits[g >> 5] = (unsigned int)(b >> (lane & 32));
    }
}

// ------- Kernel B: x-scale, h=x@W, LayerNorm, s1/s2, h fp32 + hT bf16 -------
__global__ __launch_bounds__(256) void node_transform(
    const float* __restrict__ in, const float* __restrict__ W,
    const float* __restrict__ a, const float* __restrict__ nw,
    const float* __restrict__ nb, const float* __restrict__ gam,
    const float* __restrict__ bet,
    float* __restrict__ h, float* __restrict__ s1, float* __restrict__ s2,
    unsigned short* __restrict__ hT)
{
    __shared__ float Wl[64 * 64];
    int t = threadIdx.x;
#pragma unroll
    for (int s = 0; s < 16; ++s) Wl[t + 256 * s] = W[t + 256 * s];
    __syncthreads();
    int wave = t >> 6, lane = t & 63;
    float ga = gam[lane], be = bet[lane];
    float a1 = a[lane], a2 = a[64 + lane];
    short8 h8;
#pragma unroll
    for (int nn = 0; nn < 8; ++nn) {
        int node = blockIdx.x * 32 + wave * 8 + nn;
        int n = node & (Nn - 1);
        float xv = in[node * 64 + lane] * (nw[n] + 1.0f) + nb[n];
        float hv0 = 0.f, hv1 = 0.f, hv2 = 0.f, hv3 = 0.f;
#pragma unroll
        for (int k4 = 0; k4 < 16; ++k4) {
            hv0 = fmaf(__shfl(xv, k4 * 4 + 0, 64), Wl[(k4 * 4 + 0) * 64 + lane], hv0);
            hv1 = fmaf(__shfl(xv, k4 * 4 + 1, 64), Wl[(k4 * 4 + 1) * 64 + lane], hv1);
            hv2 = fmaf(__shfl(xv, k4 * 4 + 2, 64), Wl[(k4 * 4 + 2) * 64 + lane], hv2);
            hv3 = fmaf(__shfl(xv, k4 * 4 + 3, 64), Wl[(k4 * 4 + 3) * 64 + lane], hv3);
        }
        float hv = (hv0 + hv1) + (hv2 + hv3);
        float mu = hv;
#pragma unroll
        for (int o = 32; o; o >>= 1) mu += __shfl_xor(mu, o, 64);
        mu *= (1.f / 64.f);
        float d = hv - mu;
        float var = d * d;
#pragma unroll
        for (int o = 32; o; o >>= 1) var += __shfl_xor(var, o, 64);
        var *= (1.f / 64.f);
        float hn = d * rsqrtf(var + LN_EPS) * ga + be;
        h[node * 64 + lane] = hn;
        h8[nn] = (short)f2bf(hn);
        float p1 = hn * a1, p2 = hn * a2;
#pragma unroll
        for (int o = 32; o; o >>= 1) {
            p1 += __shfl_xor(p1, o, 64);
            p2 += __shfl_xor(p2, o, 64);
        }
        if (lane == 0) { s1[node] = p1; s2[node] = p2; }
    }
    int node0 = blockIdx.x * 32;
    int b = node0 >> 11, col = (node0 & (Nn - 1)) + wave * 8;
    *(short8*)&hT[((size_t)(b * 64 + lane)) * Nn + col] = h8;
}

// ---- Kernel C: barrier-free fused softmax + MFMA PV, spill-free pipeline ----
// grid (64, 8): 32 rows/block, 512 thr = 8 waves: wave = (rg = w&1, jq = w>>1).
__global__ __launch_bounds__(512) void attention4(
    const float* __restrict__ h, const unsigned short* __restrict__ hT,
    const float* __restrict__ s1g, const float* __restrict__ s2g,
    const unsigned int* __restrict__ bits, float* __restrict__ out)
{
    __shared__ float paccl[2][4][16][68];   // [rg][jq][row][f] padded
    __shared__ float zl[2][4][16];

    int t = threadIdx.x, wave = t >> 6, lane = t & 63;
    int am = lane & 15, ag = lane >> 4;
    int rg = wave & 1, jq = wave >> 1;
    int b = blockIdx.y;
    int i0 = blockIdx.x * 32 + rg * 16;
    int row = i0 + am;

    float s1r = s1g[b * Nn + row];
    const unsigned int* brow = bits + (size_t)row * 64 + jq * 16;       // per-lane row
    const float* s2q = s2g + b * Nn + jq * 512 + 8 * ag;                // ag-uniform
    const unsigned short* hTq = hT + ((size_t)(b * 64) + am) * Nn + jq * 512 + 8 * ag;
    const unsigned short* hT0 = hTq;
    const unsigned short* hT1 = hTq + (size_t)16 * Nn;
    const unsigned short* hT2 = hTq + (size_t)32 * Nn;
    const unsigned short* hT3 = hTq + (size_t)48 * Nn;

    f32x4 acc0 = {0,0,0,0}, acc1 = {0,0,0,0}, acc2 = {0,0,0,0}, acc3 = {0,0,0,0};
    float zp = 0.f;

#define PSTEP(W, F0, F1, F2, F3) do {                                       \
        unsigned wd = brow[W];                                              \
        float4 sa = *(const float4*)&s2q[(W) * 32];                         \
        float4 sb = *(const float4*)&s2q[(W) * 32 + 4];                     \
        float se[8] = {sa.x, sa.y, sa.z, sa.w, sb.x, sb.y, sb.z, sb.w};     \
        short8 af;                                                          \
        _Pragma("unroll")                                                   \
        for (int e = 0; e < 8; ++e) {                                       \
            float x = s1r + se[e];                                          \
            float lr = fmaxf(x, ALPHA * x);                                 \
            float p = ((wd >> (8 * ag + e)) & 1u) ? __expf(lr) : 0.f;       \
            zp += p;                                                        \
            af[e] = (short)f2bf(p);                                         \
        }                                                                   \
        acc0 = __builtin_amdgcn_mfma_f32_16x16x32_bf16(af, F0, acc0, 0,0,0);\
        acc1 = __builtin_amdgcn_mfma_f32_16x16x32_bf16(af, F1, acc1, 0,0,0);\
        acc2 = __builtin_amdgcn_mfma_f32_16x16x32_bf16(af, F2, acc2, 0,0,0);\
        acc3 = __builtin_amdgcn_mfma_f32_16x16x32_bf16(af, F3, acc3, 0,0,0);\
    } while (0)

    short8 A0 = *(const short8*)&hT0[0];
    short8 A1 = *(const short8*)&hT1[0];
    short8 A2 = *(const short8*)&hT2[0];
    short8 A3 = *(const short8*)&hT3[0];

#pragma unroll
    for (int w2 = 0; w2 < 8; ++w2) {
        const int wa = 2 * w2, wb = 2 * w2 + 1;
        short8 B0 = *(const short8*)&hT0[wb * 32];
        short8 B1 = *(const short8*)&hT1[wb * 32];
        short8 B2 = *(const short8*)&hT2[wb * 32];
        short8 B3 = *(const short8*)&hT3[wb * 32];
        PSTEP(wa, A0, A1, A2, A3);
        if (w2 < 7) {
            A0 = *(const short8*)&hT0[(wb + 1) * 32];
            A1 = *(const short8*)&hT1[(wb + 1) * 32];
            A2 = *(const short8*)&hT2[(wb + 1) * 32];
            A3 = *(const short8*)&hT3[(wb + 1) * 32];
        }
        PSTEP(wb, B0, B1, B2, B3);
    }
#undef PSTEP

    // Z partial for row am: reduce over ag groups
    zp += __shfl_xor(zp, 16, 64);
    zp += __shfl_xor(zp, 32, 64);
    if (lane < 16) zl[rg][jq][am] = zp;

    // acc tiles -> LDS: row_local = ag*4+q, f = fb*16+am
#pragma unroll
    for (int q = 0; q < 4; ++q) {
        paccl[rg][jq][ag * 4 + q][0 * 16 + am] = acc0[q];
        paccl[rg][jq][ag * 4 + q][1 * 16 + am] = acc1[q];
        paccl[rg][jq][ag * 4 + q][2 * 16 + am] = acc2[q];
        paccl[rg][jq][ag * 4 + q][3 * 16 + am] = acc3[q];
    }
    __syncthreads();

    // combine over jq + residual + elu. 512 thr over 32 rows x 16 fquads.
    int rl = t >> 4, fq = t & 15;
    int rg2 = rl >> 4, r16 = rl & 15;
    float zs = zl[rg2][0][r16] + zl[rg2][1][r16] + zl[rg2][2][r16] + zl[rg2][3][r16];
    float sx = 0.f, sy = 0.f, sz = 0.f, sw = 0.f;
#pragma unroll
    for (int q4 = 0; q4 < 4; ++q4) {
        const float* p = &paccl[rg2][q4][r16][fq * 4];
        sx += p[0]; sy += p[1]; sz += p[2]; sw += p[3];
    }
    float zinv = 1.f / zs;
    int gi = blockIdx.x * 32 + rl;
    size_t base = ((size_t)(blockIdx.y * Nn + gi)) * 64 + fq * 4;
    float4 hv = *(const float4*)&h[base];
    float4 o;
    o.x = sx * zinv + hv.x; o.x = o.x > 0.f ? o.x : expm1f(o.x);
    o.y = sy * zinv + hv.y; o.y = o.y > 0.f ? o.y : expm1f(o.y);
    o.z = sz * zinv + hv.z; o.z = o.z > 0.f ? o.z : expm1f(o.z);
    o.w = sw * zinv + hv.w; o.w = o.w > 0.f ? o.w : expm1f(o.w);
    *(float4*)&out[base] = o;
}

// ---------------- launch ----------------
extern "C" void kernel_launch(void* const* d_in, const int* in_sizes, int n_in,
                              void* d_out, int out_size, void* d_ws, size_t ws_size,
                              hipStream_t stream) {
    const float* in  = (const float*)d_in[0];
    const int*   adj = (const int*)d_in[1];
    const float* W   = (const float*)d_in[2];
    const float* a   = (const float*)d_in[3];
    const float* nw  = (const float*)d_in[4];
    const float* nb  = (const float*)d_in[5];
    const float* gam = (const float*)d_in[6];
    const float* bet = (const float*)d_in[7];
    float* out = (float*)d_out;

    char* ws = (char*)d_ws;
    float* h  = (float*)ws;                                      // 4 MB
    float* s1 = (float*)(ws + (size_t)Bb * Nn * Ff * 4);         // 64 KB
    float* s2 = s1 + (size_t)Bb * Nn;                            // 64 KB
    unsigned int* bits = (unsigned int*)(s2 + (size_t)Bb * Nn);  // 512 KB
    unsigned short* hT = (unsigned short*)(bits + (size_t)Nn * Nn / 32); // 2 MB

    hipLaunchKernelGGL(pack_mask, dim3(Nn * Nn / 256), dim3(256), 0, stream, adj, bits);
    hipLaunchKernelGGL(node_transform, dim3(Bb * Nn / 32), dim3(256), 0, stream,
                       in, W, a, nw, nb, gam, bet, h, s1, s2, hT);
    hipLaunchKernelGGL(attention4, dim3(Nn / 32, Bb), dim3(512), 0, stream,
                       h, hT, s1, s2, bits, out);
}

// Round 5
// 59.818 us; speedup vs baseline: 4.0664x; 1.2600x over previous
//
#include <hip/hip_runtime.h>
#include <math.h>

#define Bb 8
#define Nn 2048
#define Ff 64
#define ALPHA 0.2f
#define LN_EPS 1e-5f

typedef __attribute__((ext_vector_type(8))) short short8;
typedef __attribute__((ext_vector_type(4))) float f32x4;

__device__ inline unsigned short f2bf(float f) {
    unsigned u = __builtin_bit_cast(unsigned, f);
    u += 0x7fffu + ((u >> 16) & 1u);   // round-to-nearest-even
    return (unsigned short)(u >> 16);
}

// ------ Kernel A: pack adj into TRANSPOSED bitmask bitsT[i>>4][w][i&15] ------
__global__ __launch_bounds__(256) void pack_mask(const int* __restrict__ adj,
                                                 unsigned int* __restrict__ bitsT) {
    int g = blockIdx.x * blockDim.x + threadIdx.x;
    int lane = threadIdx.x & 63;
    int pred = adj[g] > 0;
    unsigned long long b = __ballot(pred);
    if ((lane & 31) == 0) {
        unsigned w32 = (unsigned)(b >> (lane & 32));
        int i = g >> 11, w = (g >> 5) & 63;
        bitsT[((size_t)(i >> 4) * 64 + w) * 16 + (i & 15)] = w32;
    }
}

// -- Kernel B: x-scale, h=x@W, LayerNorm, s1/s2, h fp32 + FRAGMENT-TILED hT2 --
// hT2[b][jw][fb][fraglane][e]: frag for (jw,fb), lane (am,ag) holds
// h[j = jw*32+8*ag+e][f = fb*16+am] as bf16. Producer wave==ag, lane==f, nn==e.
__global__ __launch_bounds__(256) void node_transform(
    const float* __restrict__ in, const float* __restrict__ W,
    const float* __restrict__ a, const float* __restrict__ nw,
    const float* __restrict__ nb, const float* __restrict__ gam,
    const float* __restrict__ bet,
    float* __restrict__ h, float* __restrict__ s1, float* __restrict__ s2,
    unsigned short* __restrict__ hT2)
{
    __shared__ float Wl[64 * 64];
    int t = threadIdx.x;
#pragma unroll
    for (int s = 0; s < 16; ++s) Wl[t + 256 * s] = W[t + 256 * s];
    __syncthreads();
    int wave = t >> 6, lane = t & 63;
    float ga = gam[lane], be = bet[lane];
    float a1 = a[lane], a2 = a[64 + lane];
    short8 h8;
#pragma unroll
    for (int nn = 0; nn < 8; ++nn) {
        int node = blockIdx.x * 32 + wave * 8 + nn;
        int n = node & (Nn - 1);
        float xv = in[node * 64 + lane] * (nw[n] + 1.0f) + nb[n];
        float hv0 = 0.f, hv1 = 0.f, hv2 = 0.f, hv3 = 0.f;
#pragma unroll
        for (int k4 = 0; k4 < 16; ++k4) {
            hv0 = fmaf(__shfl(xv, k4 * 4 + 0, 64), Wl[(k4 * 4 + 0) * 64 + lane], hv0);
            hv1 = fmaf(__shfl(xv, k4 * 4 + 1, 64), Wl[(k4 * 4 + 1) * 64 + lane], hv1);
            hv2 = fmaf(__shfl(xv, k4 * 4 + 2, 64), Wl[(k4 * 4 + 2) * 64 + lane], hv2);
            hv3 = fmaf(__shfl(xv, k4 * 4 + 3, 64), Wl[(k4 * 4 + 3) * 64 + lane], hv3);
        }
        float hv = (hv0 + hv1) + (hv2 + hv3);
        float mu = hv;
#pragma unroll
        for (int o = 32; o; o >>= 1) mu += __shfl_xor(mu, o, 64);
        mu *= (1.f / 64.f);
        float d = hv - mu;
        float var = d * d;
#pragma unroll
        for (int o = 32; o; o >>= 1) var += __shfl_xor(var, o, 64);
        var *= (1.f / 64.f);
        float hn = d * rsqrtf(var + LN_EPS) * ga + be;
        h[node * 64 + lane] = hn;
        h8[nn] = (short)f2bf(hn);
        float p1 = hn * a1, p2 = hn * a2;
#pragma unroll
        for (int o = 32; o; o >>= 1) {
            p1 += __shfl_xor(p1, o, 64);
            p2 += __shfl_xor(p2, o, 64);
        }
        if (lane == 0) { s1[node] = p1; s2[node] = p2; }
    }
    // fragment-tiled write: slab (b, jw, fb=lane>>4), fraglane = wave*16+(lane&15)
    int node0 = blockIdx.x * 32;
    int b = node0 >> 11;
    int jw = (node0 & (Nn - 1)) >> 5;
    size_t base = (((size_t)(b * 64 + jw) * 4 + (lane >> 4)) * 64 + (wave * 16 + (lane & 15))) * 8;
    *(short8*)&hT2[base] = h8;
}

// ---- Kernel C: barrier-free fused softmax + MFMA PV, coalesced loads --------
// grid (64, 8): 32 rows/block, 512 thr = 8 waves: wave = (rg = w&1, jq = w>>1).
__global__ __launch_bounds__(512) void attention4(
    const float* __restrict__ h, const unsigned short* __restrict__ hT2,
    const float* __restrict__ s1g, const float* __restrict__ s2g,
    const unsigned int* __restrict__ bitsT, float* __restrict__ out)
{
    __shared__ float paccl[2][4][16][68];   // [rg][jq][row][f] padded
    __shared__ float zl[2][4][16];

    int t = threadIdx.x, wave = t >> 6, lane = t & 63;
    int am = lane & 15, ag = lane >> 4;
    int rg = wave & 1, jq = wave >> 1;
    int b = blockIdx.y;
    int i0 = blockIdx.x * 32 + rg * 16;
    int row = i0 + am;

    float s1r = s1g[b * Nn + row];
    // bitsT: word W for this wave at btq[W*16]; am-lanes are consecutive dwords
    const unsigned int* btq = bitsT + ((size_t)(blockIdx.x * 2 + rg) * 64 + jq * 16) * 16 + am;
    const float* s2q = s2g + b * Nn + jq * 512 + 8 * ag;               // ag-uniform
    // hT2: per-PSTEP fragment = 64 lanes x 16B contiguous
    const unsigned short* fq = hT2 + ((size_t)(b * 64 + jq * 16) * 4) * 512 + lane * 8;

    f32x4 acc0 = {0,0,0,0}, acc1 = {0,0,0,0}, acc2 = {0,0,0,0}, acc3 = {0,0,0,0};
    float zp = 0.f;

#define PSTEP(W, F0, F1, F2, F3) do {                                       \
        unsigned wd = btq[(W) * 16];                                        \
        float4 sa = *(const float4*)&s2q[(W) * 32];                         \
        float4 sb = *(const float4*)&s2q[(W) * 32 + 4];                     \
        float se[8] = {sa.x, sa.y, sa.z, sa.w, sb.x, sb.y, sb.z, sb.w};     \
        short8 af;                                                          \
        _Pragma("unroll")                                                   \
        for (int e = 0; e < 8; ++e) {                                       \
            float x = s1r + se[e];                                          \
            float lr = fmaxf(x, ALPHA * x);                                 \
            float p = ((wd >> (8 * ag + e)) & 1u) ? __expf(lr) : 0.f;       \
            zp += p;                                                        \
            af[e] = (short)f2bf(p);                                         \
        }                                                                   \
        acc0 = __builtin_amdgcn_mfma_f32_16x16x32_bf16(af, F0, acc0, 0,0,0);\
        acc1 = __builtin_amdgcn_mfma_f32_16x16x32_bf16(af, F1, acc1, 0,0,0);\
        acc2 = __builtin_amdgcn_mfma_f32_16x16x32_bf16(af, F2, acc2, 0,0,0);\
        acc3 = __builtin_amdgcn_mfma_f32_16x16x32_bf16(af, F3, acc3, 0,0,0);\
    } while (0)

    short8 A0 = *(const short8*)&fq[0 * 512];
    short8 A1 = *(const short8*)&fq[1 * 512];
    short8 A2 = *(const short8*)&fq[2 * 512];
    short8 A3 = *(const short8*)&fq[3 * 512];

#pragma unroll
    for (int w2 = 0; w2 < 8; ++w2) {
        const int wa = 2 * w2, wb = 2 * w2 + 1;
        short8 B0 = *(const short8*)&fq[(size_t)wb * 2048 + 0 * 512];
        short8 B1 = *(const short8*)&fq[(size_t)wb * 2048 + 1 * 512];
        short8 B2 = *(const short8*)&fq[(size_t)wb * 2048 + 2 * 512];
        short8 B3 = *(const short8*)&fq[(size_t)wb * 2048 + 3 * 512];
        PSTEP(wa, A0, A1, A2, A3);
        if (w2 < 7) {
            A0 = *(const short8*)&fq[(size_t)(wb + 1) * 2048 + 0 * 512];
            A1 = *(const short8*)&fq[(size_t)(wb + 1) * 2048 + 1 * 512];
            A2 = *(const short8*)&fq[(size_t)(wb + 1) * 2048 + 2 * 512];
            A3 = *(const short8*)&fq[(size_t)(wb + 1) * 2048 + 3 * 512];
        }
        PSTEP(wb, B0, B1, B2, B3);
    }
#undef PSTEP

    // Z partial for row am: reduce over ag groups
    zp += __shfl_xor(zp, 16, 64);
    zp += __shfl_xor(zp, 32, 64);
    if (lane < 16) zl[rg][jq][am] = zp;

    // acc tiles -> LDS: row_local = ag*4+q, f = fb*16+am
#pragma unroll
    for (int q = 0; q < 4; ++q) {
        paccl[rg][jq][ag * 4 + q][0 * 16 + am] = acc0[q];
        paccl[rg][jq][ag * 4 + q][1 * 16 + am] = acc1[q];
        paccl[rg][jq][ag * 4 + q][2 * 16 + am] = acc2[q];
        paccl[rg][jq][ag * 4 + q][3 * 16 + am] = acc3[q];
    }
    __syncthreads();

    // combine over jq + residual + elu. 512 thr over 32 rows x 16 fquads.
    int rl = t >> 4, fq2 = t & 15;
    int rg2 = rl >> 4, r16 = rl & 15;
    float zs = zl[rg2][0][r16] + zl[rg2][1][r16] + zl[rg2][2][r16] + zl[rg2][3][r16];
    float sx = 0.f, sy = 0.f, sz = 0.f, sw = 0.f;
#pragma unroll
    for (int q4 = 0; q4 < 4; ++q4) {
        const float* p = &paccl[rg2][q4][r16][fq2 * 4];
        sx += p[0]; sy += p[1]; sz += p[2]; sw += p[3];
    }
    float zinv = 1.f / zs;
    int gi = blockIdx.x * 32 + rl;
    size_t base = ((size_t)(blockIdx.y * Nn + gi)) * 64 + fq2 * 4;
    float4 hv = *(const float4*)&h[base];
    float4 o;
    o.x = sx * zinv + hv.x; o.x = o.x > 0.f ? o.x : expm1f(o.x);
    o.y = sy * zinv + hv.y; o.y = o.y > 0.f ? o.y : expm1f(o.y);
    o.z = sz * zinv + hv.z; o.z = o.z > 0.f ? o.z : expm1f(o.z);
    o.w = sw * zinv + hv.w; o.w = o.w > 0.f ? o.w : expm1f(o.w);
    *(float4*)&out[base] = o;
}

// ---------------- launch ----------------
extern "C" void kernel_launch(void* const* d_in, const int* in_sizes, int n_in,
                              void* d_out, int out_size, void* d_ws, size_t ws_size,
                              hipStream_t stream) {
    const float* in  = (const float*)d_in[0];
    const int*   adj = (const int*)d_in[1];
    const float* W   = (const float*)d_in[2];
    const float* a   = (const float*)d_in[3];
    const float* nw  = (const float*)d_in[4];
    const float* nb  = (const float*)d_in[5];
    const float* gam = (const float*)d_in[6];
    const float* bet = (const float*)d_in[7];
    float* out = (float*)d_out;

    char* ws = (char*)d_ws;
    float* h  = (float*)ws;                                      // 4 MB
    float* s1 = (float*)(ws + (size_t)Bb * Nn * Ff * 4);         // 64 KB
    float* s2 = s1 + (size_t)Bb * Nn;                            // 64 KB
    unsigned int* bitsT = (unsigned int*)(s2 + (size_t)Bb * Nn); // 512 KB
    unsigned short* hT2 = (unsigned short*)(bitsT + (size_t)Nn * Nn / 32); // 2 MB

    hipLaunchKernelGGL(pack_mask, dim3(Nn * Nn / 256), dim3(256), 0, stream, adj, bitsT);
    hipLaunchKernelGGL(node_transform, dim3(Bb * Nn / 32), dim3(256), 0, stream,
                       in, W, a, nw, nb, gam, bet, h, s1, s2, hT2);
    hipLaunchKernelGGL(attention4, dim3(Nn / 32, Bb), dim3(512), 0, stream,
                       h, hT2, s1, s2, bitsT, out);
}